// Round 4
// baseline (1143.102 us; speedup 1.0000x reference)
//
#include <hip/hip_runtime.h>
#include <hip/hip_bf16.h>
#include <math.h>

#define E_NUM 800000
#define NN 50000
#define NG 50
#define TILE_E 128
#define N_TILES (E_NUM / TILE_E)
#define EDGE_GRID 512

typedef __bf16 bf16x8 __attribute__((ext_vector_type(8)));
typedef float f32x4 __attribute__((ext_vector_type(4)));
typedef unsigned short ushortx8 __attribute__((ext_vector_type(8)));

__device__ __forceinline__ unsigned short f2b(float f) {
  union { float f; unsigned u; } v; v.f = f;
  unsigned u = v.u;
  u += 0x7fffu + ((u >> 16) & 1u);
  return (unsigned short)(u >> 16);
}
__device__ __forceinline__ float b2f(unsigned short u) {
  union { unsigned u; float f; } v; v.u = ((unsigned)u) << 16; return v.f;
}

// shifted softplus via hw exp2/log2
__device__ __forceinline__ float sspf(float v) {
  float e = __builtin_amdgcn_exp2f(-1.4426950408889634f * fabsf(v));
  return fmaxf(v, 0.f) + 0.6931471805599453f * __builtin_amdgcn_logf(fmaf(0.5f, e, 0.5f));
}

// ---------------- sort pipeline: counting sort of edges by dst ----------------
__global__ __launch_bounds__(256) void k_hist(const int* __restrict__ ei, int* __restrict__ counts) {
  int e = blockIdx.x * 256 + threadIdx.x;
  if (e < E_NUM) atomicAdd(&counts[ei[E_NUM + e]], 1);
}

__global__ __launch_bounds__(1024) void k_scan(const int* __restrict__ counts, int* __restrict__ cursor) {
  __shared__ int tot[1024];
  const int t = threadIdx.x;
  const int C = (NN + 1023) >> 10;  // 49
  int lo = t * C, hi = lo + C; if (hi > NN) hi = NN; if (lo > NN) lo = NN;
  int s = 0;
  for (int i = lo; i < hi; ++i) s += counts[i];
  tot[t] = s;
  __syncthreads();
  int mine = s;
  for (int off = 1; off < 1024; off <<= 1) {
    int v = (t >= off) ? tot[t - off] : 0;
    __syncthreads();
    tot[t] += v;
    __syncthreads();
  }
  int run = tot[t] - mine;  // exclusive prefix of this chunk
  for (int i = lo; i < hi; ++i) { int c = counts[i]; cursor[i] = run; run += c; }
}

__global__ __launch_bounds__(256) void k_scatter(const int* __restrict__ ei,
                                                 int* __restrict__ cursor, int* __restrict__ perm) {
  int e = blockIdx.x * 256 + threadIdx.x;
  if (e < E_NUM) {
    int d = ei[E_NUM + e];
    int pos = atomicAdd(&cursor[d], 1);
    perm[pos] = e;
  }
}

// ---------------- node GEMM (bf16 MFMA, 128-node blocks) ----------------
__global__ __launch_bounds__(256) void k_mfma_gemm(
    const float* __restrict__ X, const float* __restrict__ Wm,
    const float* __restrict__ bias, float* __restrict__ out, int act, int nrows)
{
  __shared__ __attribute__((aligned(16))) unsigned short s_x[128 * 128];
  __shared__ __attribute__((aligned(16))) unsigned short s_w[128 * 128];
  const int tid = threadIdx.x;
  const int w = tid >> 6, lane = tid & 63, q = lane >> 4, n16 = lane & 15;
  const int base = blockIdx.x * 128;

  for (int c = tid; c < 128 * 16; c += 256) {
    int f = c >> 4, ch = c & 15;
    const float4* wp = (const float4*)(Wm + f * 128 + ch * 8);
    float4 v0 = wp[0], v1 = wp[1];
    ushortx8 v = { f2b(v0.x), f2b(v0.y), f2b(v0.z), f2b(v0.w),
                   f2b(v1.x), f2b(v1.y), f2b(v1.z), f2b(v1.w) };
    *(ushortx8*)&s_w[(f << 7) + ((ch ^ (f & 15)) << 3)] = v;
  }
  for (int c = tid; c < 128 * 16; c += 256) {
    int r = c >> 4, ch = c & 15;
    int n = base + r;
    float4 v0 = {0.f, 0.f, 0.f, 0.f}, v1 = v0;
    if (n < nrows) {
      const float4* xp = (const float4*)(X + (long)n * 128 + ch * 8);
      v0 = xp[0]; v1 = xp[1];
    }
    ushortx8 v = { f2b(v0.x), f2b(v0.y), f2b(v0.z), f2b(v0.w),
                   f2b(v1.x), f2b(v1.y), f2b(v1.z), f2b(v1.w) };
    *(ushortx8*)&s_x[(r << 7) + ((ch ^ (r & 15)) << 3)] = v;
  }
  __syncthreads();

  float bv[8];
#pragma unroll
  for (int t = 0; t < 8; ++t) bv[t] = bias ? bias[t * 16 + n16] : 0.f;

  bf16x8 a[2][4];
#pragma unroll
  for (int g = 0; g < 2; ++g) {
    int r = w * 32 + g * 16 + n16;
#pragma unroll
    for (int ks = 0; ks < 4; ++ks)
      a[g][ks] = *(const bf16x8*)&s_x[(r << 7) + (((ks * 4 + q) ^ (r & 15)) << 3)];
  }
#pragma unroll
  for (int t = 0; t < 8; ++t) {
    int f = t * 16 + n16;
    bf16x8 b[4];
#pragma unroll
    for (int ks = 0; ks < 4; ++ks)
      b[ks] = *(const bf16x8*)&s_w[(f << 7) + (((ks * 4 + q) ^ (f & 15)) << 3)];
#pragma unroll
    for (int g = 0; g < 2; ++g) {
      f32x4 acc = {0.f, 0.f, 0.f, 0.f};
#pragma unroll
      for (int ks = 0; ks < 4; ++ks)
        acc = __builtin_amdgcn_mfma_f32_16x16x32_bf16(a[g][ks], b[ks], acc, 0, 0, 0);
#pragma unroll
      for (int r = 0; r < 4; ++r) {
        int n = base + w * 32 + g * 16 + q * 4 + r;
        if (n < nrows) {
          float v = acc[r] + bv[t];
          if (act) v = sspf(v);
          out[(long)n * 128 + f] = v;
        }
      }
    }
  }
}

// ---------------- edge kernel: dst-sorted tiles, MFMA MLP, run-reduced scatter ----------------
__global__ __launch_bounds__(256, 2) void k_edge(
    const float* __restrict__ attr,   // [E][50]
    const int*   __restrict__ ei,     // [2][E]
    const float* __restrict__ ew,     // [E]
    const float* __restrict__ w1,     // [128][50]
    const float* __restrict__ b1,     // [128]
    const float* __restrict__ w2,     // [128][128]
    const float* __restrict__ b2,     // [128]
    const float* __restrict__ h,      // [NN][128]
    const int*   __restrict__ perm,   // [E] edge ids sorted by dst
    float*       __restrict__ agg)    // [NN][128]
{
  __shared__ __attribute__((aligned(16))) unsigned short s_he[128 * 128]; // 32 KB: attr->h_e->msg
  __shared__ __attribute__((aligned(16))) unsigned short s_w2[128 * 128]; // 32 KB
  __shared__ int   s_src[128];
  __shared__ int   s_dst[128];
  __shared__ float s_cv[128];

  const int tid  = threadIdx.x;
  const int w    = tid >> 6;
  const int lane = tid & 63;
  const int q    = lane >> 4;
  const int n16  = lane & 15;

  // stage w2 once (bf16, XOR-chunk swizzle)
  for (int i = tid; i < 128 * 128; i += 256) {
    int f = i >> 7, k = i & 127;
    int pos = (f << 7) + ((((k >> 3) ^ (f & 15)) << 3)) + (k & 7);
    s_w2[pos] = f2b(w2[i]);
  }
  // w1 B-fragments in registers (once): f = 16t+n16; bA: k=8q.. ; bB: k=32+8q..
  bf16x8 w1A[8], w1B[8];
#pragma unroll
  for (int t = 0; t < 8; ++t) {
    int f = t * 16 + n16;
    const float* row = w1 + f * NG;
    float ta[8], tb[8];
#pragma unroll
    for (int j = 0; j < 8; ++j) ta[j] = row[q * 8 + j];            // k<=31 always valid
#pragma unroll
    for (int j = 0; j < 8; ++j) { int k = 32 + q * 8 + j; tb[j] = (k < NG) ? row[k] : 0.f; }
    union { ushortx8 u; bf16x8 b; } ua, ub;
#pragma unroll
    for (int j = 0; j < 8; ++j) { ua.u[j] = f2b(ta[j]); ub.u[j] = f2b(tb[j]); }
    w1A[t] = ua.b; w1B[t] = ub.b;
  }
  float b1v[8], b2v[8];
#pragma unroll
  for (int t = 0; t < 8; ++t) {
    b1v[t] = b1[t * 16 + n16];
    b2v[t] = b2[t * 16 + n16];
  }

  for (int tile = blockIdx.x; tile < N_TILES; tile += gridDim.x) {
    const int e0 = tile * TILE_E;
    __syncthreads();  // prior tile fully consumed s_he/s_dst

    // stage per-edge metadata (sorted order)
    if (tid < 128) {
      int e = perm[e0 + tid];
      s_src[tid] = ei[e];
      s_dst[tid] = ei[E_NUM + e];
      // C = 0.5*(cos(ew*pi/10)+1); v_cos takes revolutions -> ew*0.05
      s_cv[tid] = 0.5f * (__builtin_amdgcn_cosf(ew[e] * 0.05f) + 1.f);
    }
    // stage attr tile: row gather via perm, 128x64 bf16, zero-pad, swizzled
    for (int i = tid; i < 128 * 64; i += 256) {
      int eL = i >> 6, k = i & 63;
      int e = perm[e0 + eL];   // wave-uniform address (64 lanes share eL)
      float v = (k < NG) ? attr[(long)e * NG + k] : 0.f;
      int pos = (eL << 6) + ((((k >> 3) ^ (eL & 7)) << 3)) + (k & 7);
      s_he[pos] = f2b(v);
    }
    __syncthreads();

    // layer-1 A fragments
    bf16x8 a1f[2][2];
#pragma unroll
    for (int g = 0; g < 2; ++g) {
      int er = w * 32 + g * 16 + n16;
      a1f[g][0] = *(const bf16x8*)&s_he[(er << 6) + (((q    ) ^ (er & 7)) << 3)];
      a1f[g][1] = *(const bf16x8*)&s_he[(er << 6) + (((4 + q) ^ (er & 7)) << 3)];
    }
    __syncthreads();  // attr in regs; s_he reusable as h_e

    // layer 1: h_e = ssp(attr @ w1^T + b1) -> LDS A-layout
#pragma unroll
    for (int t = 0; t < 8; ++t) {
      int kf = t * 16 + n16;
#pragma unroll
      for (int g = 0; g < 2; ++g) {
        f32x4 acc = {0.f, 0.f, 0.f, 0.f};
        acc = __builtin_amdgcn_mfma_f32_16x16x32_bf16(a1f[g][0], w1A[t], acc, 0, 0, 0);
        acc = __builtin_amdgcn_mfma_f32_16x16x32_bf16(a1f[g][1], w1B[t], acc, 0, 0, 0);
#pragma unroll
        for (int r = 0; r < 4; ++r) {
          int e = w * 32 + g * 16 + q * 4 + r;
          float hv = sspf(acc[r] + b1v[t]);
          int pos = (e << 7) + ((((kf >> 3) ^ (e & 15)) << 3)) + (kf & 7);
          s_he[pos] = f2b(hv);
        }
      }
    }
    __syncthreads();

    // layer-2 A fragments
    bf16x8 a2f[2][4];
#pragma unroll
    for (int g = 0; g < 2; ++g) {
      int er = w * 32 + g * 16 + n16;
#pragma unroll
      for (int ks = 0; ks < 4; ++ks)
        a2f[g][ks] = *(const bf16x8*)&s_he[(er << 7) + (((ks * 4 + q) ^ (er & 15)) << 3)];
    }
    __syncthreads();  // h_e consumed; s_he becomes msg region

    // layer 2 + msg into LDS: msg[e][f] = h[src[e]][f] * (h_e@w2^T + b2)[e][f] * cv[e]
#pragma unroll
    for (int t = 0; t < 8; ++t) {
      int f = t * 16 + n16;
      bf16x8 bb[4];
#pragma unroll
      for (int ks = 0; ks < 4; ++ks)
        bb[ks] = *(const bf16x8*)&s_w2[(f << 7) + (((ks * 4 + q) ^ (f & 15)) << 3)];
#pragma unroll
      for (int g = 0; g < 2; ++g) {
        f32x4 acc = {0.f, 0.f, 0.f, 0.f};
#pragma unroll
        for (int ks = 0; ks < 4; ++ks)
          acc = __builtin_amdgcn_mfma_f32_16x16x32_bf16(a2f[g][ks], bb[ks], acc, 0, 0, 0);
#pragma unroll
        for (int r = 0; r < 4; ++r) {
          int eL = w * 32 + g * 16 + q * 4 + r;
          float Wv = (acc[r] + b2v[t]) * s_cv[eL];
          float msg = h[(long)s_src[eL] * 128 + f] * Wv;
          s_he[eL * 128 + f] = f2b(msg);
        }
      }
    }
    __syncthreads();

    // run-segmented reduction over sorted dst; wave-uniform control flow
    {
      int f = tid & 127, half = tid >> 7;
      int eS = half * 64, eE = eS + 64;
      float acc = 0.f;
      for (int e = eS; e < eE; ++e) {
        acc += b2f(s_he[e * 128 + f]);
        int d = s_dst[e];
        int dn = (e + 1 < eE) ? s_dst[e + 1] : -1;
        if (d != dn) { atomicAdd(&agg[(long)d * 128 + f], acc); acc = 0.f; }
      }
    }
  }
}

extern "C" void kernel_launch(void* const* d_in, const int* in_sizes, int n_in,
                              void* d_out, int out_size, void* d_ws, size_t ws_size,
                              hipStream_t stream) {
  const float* x     = (const float*)d_in[0];
  const int*   ei    = (const int*)  d_in[1];
  const float* ew    = (const float*)d_in[2];
  const float* attr  = (const float*)d_in[3];
  const float* w1    = (const float*)d_in[4];
  const float* b1    = (const float*)d_in[5];
  const float* w2    = (const float*)d_in[6];
  const float* b2    = (const float*)d_in[7];
  const float* lin1w = (const float*)d_in[8];
  const float* lin2w = (const float*)d_in[9];
  const float* lin2b = (const float*)d_in[10];
  const float* linw  = (const float*)d_in[11];
  const float* linb  = (const float*)d_in[12];
  float* out = (float*)d_out;

  float* agg   = (float*)d_ws;                      // 6.4M floats
  float* h     = agg + (size_t)NN * 128;            // 6.4M floats (reused as h2)
  int*  counts = (int*)(h + (size_t)NN * 128);      // 50k
  int*  cursor = counts + NN;                       // 50k
  int*  perm   = cursor + NN;                       // 800k

  const int gemm_grid = (NN + 127) / 128;
  (void)hipMemsetAsync(agg, 0, (size_t)NN * 128 * sizeof(float), stream);
  (void)hipMemsetAsync(counts, 0, (size_t)NN * sizeof(int), stream);
  k_hist<<<(E_NUM + 255) / 256, 256, 0, stream>>>(ei, counts);
  k_scan<<<1, 1024, 0, stream>>>(counts, cursor);
  k_scatter<<<(E_NUM + 255) / 256, 256, 0, stream>>>(ei, cursor, perm);
  k_mfma_gemm<<<gemm_grid, 256, 0, stream>>>(x, lin1w, nullptr, h, 0, NN);
  k_edge<<<EDGE_GRID, 256, 0, stream>>>(attr, ei, ew, w1, b1, w2, b2, h, perm, agg);
  k_mfma_gemm<<<gemm_grid, 256, 0, stream>>>(agg, lin2w, lin2b, h, 1, NN);
  k_mfma_gemm<<<gemm_grid, 256, 0, stream>>>(h, linw, linb, out, 0, NN);
}

// Round 5
// 713.590 us; speedup vs baseline: 1.6019x; 1.6019x over previous
//
#include <hip/hip_runtime.h>
#include <hip/hip_bf16.h>
#include <math.h>

#define E_NUM 800000
#define NN 50000
#define NG 50
#define NTW (E_NUM / 16)        // 16-edge wave-tiles
#define EDGE_BLOCKS 768         // 3 blocks/CU

typedef __bf16 bf16x8 __attribute__((ext_vector_type(8)));
typedef float f32x4 __attribute__((ext_vector_type(4)));
typedef unsigned short ushortx8 __attribute__((ext_vector_type(8)));

__device__ __forceinline__ unsigned short f2b(float f) {
  union { float f; unsigned u; } v; v.f = f;
  unsigned u = v.u;
  u += 0x7fffu + ((u >> 16) & 1u);
  return (unsigned short)(u >> 16);
}
__device__ __forceinline__ float b2f(unsigned short u) {
  union { unsigned u; float f; } v; v.u = ((unsigned)u) << 16; return v.f;
}
// shifted softplus via hw exp2/log2
__device__ __forceinline__ float sspf(float v) {
  float e = __builtin_amdgcn_exp2f(-1.4426950408889634f * fabsf(v));
  return fmaxf(v, 0.f) + 0.6931471805599453f * __builtin_amdgcn_logf(fmaf(0.5f, e, 0.5f));
}

// ---------------- counting sort by dst ----------------
__global__ __launch_bounds__(256) void k_hist(const int* __restrict__ ei, int* __restrict__ counts) {
  int e = blockIdx.x * 256 + threadIdx.x;
  if (e < E_NUM) atomicAdd(&counts[ei[E_NUM + e]], 1);
}

__global__ __launch_bounds__(1024) void k_scan(const int* __restrict__ counts,
                                               int* __restrict__ cursor, int* __restrict__ off) {
  __shared__ int tot[1024];
  const int t = threadIdx.x;
  const int C = (NN + 1023) >> 10;  // 49
  int lo = t * C, hi = lo + C; if (hi > NN) hi = NN; if (lo > NN) lo = NN;
  int s = 0;
  for (int i = lo; i < hi; ++i) s += counts[i];
  tot[t] = s;
  __syncthreads();
  int mine = s;
  for (int o = 1; o < 1024; o <<= 1) {
    int v = (t >= o) ? tot[t - o] : 0;
    __syncthreads();
    tot[t] += v;
    __syncthreads();
  }
  int run = tot[t] - mine;
  for (int i = lo; i < hi; ++i) { int c = counts[i]; cursor[i] = run; off[i] = run; run += c; }
  if (t == 1023) off[NN] = E_NUM;
}

__global__ __launch_bounds__(256) void k_scatter2(const int* __restrict__ ei, const float* __restrict__ ew,
                                                  int* __restrict__ cursor, int* __restrict__ inv,
                                                  int* __restrict__ srcS, float* __restrict__ cvS) {
  int e = blockIdx.x * 256 + threadIdx.x;
  if (e < E_NUM) {
    int d = ei[E_NUM + e];
    int pos = atomicAdd(&cursor[d], 1);
    inv[e] = pos;
    srcS[pos] = ei[e];
    cvS[pos] = 0.5f * (__builtin_amdgcn_cosf(ew[e] * 0.05f) + 1.f);
  }
}

// ---------------- node GEMM (bf16 MFMA, 128-node blocks) ----------------
__global__ __launch_bounds__(256) void k_mfma_gemm(
    const float* __restrict__ X, const float* __restrict__ Wm,
    const float* __restrict__ bias, float* __restrict__ out, int act, int nrows)
{
  __shared__ __attribute__((aligned(16))) unsigned short s_x[128 * 128];
  __shared__ __attribute__((aligned(16))) unsigned short s_w[128 * 128];
  const int tid = threadIdx.x;
  const int w = tid >> 6, lane = tid & 63, q = lane >> 4, n16 = lane & 15;
  const int base = blockIdx.x * 128;

  for (int c = tid; c < 128 * 16; c += 256) {
    int f = c >> 4, ch = c & 15;
    const float4* wp = (const float4*)(Wm + f * 128 + ch * 8);
    float4 v0 = wp[0], v1 = wp[1];
    ushortx8 v = { f2b(v0.x), f2b(v0.y), f2b(v0.z), f2b(v0.w),
                   f2b(v1.x), f2b(v1.y), f2b(v1.z), f2b(v1.w) };
    *(ushortx8*)&s_w[(f << 7) + ((ch ^ (f & 15)) << 3)] = v;
  }
  for (int c = tid; c < 128 * 16; c += 256) {
    int r = c >> 4, ch = c & 15;
    int n = base + r;
    float4 v0 = {0.f, 0.f, 0.f, 0.f}, v1 = v0;
    if (n < nrows) {
      const float4* xp = (const float4*)(X + (long)n * 128 + ch * 8);
      v0 = xp[0]; v1 = xp[1];
    }
    ushortx8 v = { f2b(v0.x), f2b(v0.y), f2b(v0.z), f2b(v0.w),
                   f2b(v1.x), f2b(v1.y), f2b(v1.z), f2b(v1.w) };
    *(ushortx8*)&s_x[(r << 7) + ((ch ^ (r & 15)) << 3)] = v;
  }
  __syncthreads();

  float bv[8];
#pragma unroll
  for (int t = 0; t < 8; ++t) bv[t] = bias ? bias[t * 16 + n16] : 0.f;

  bf16x8 a[2][4];
#pragma unroll
  for (int g = 0; g < 2; ++g) {
    int r = w * 32 + g * 16 + n16;
#pragma unroll
    for (int ks = 0; ks < 4; ++ks)
      a[g][ks] = *(const bf16x8*)&s_x[(r << 7) + (((ks * 4 + q) ^ (r & 15)) << 3)];
  }
#pragma unroll
  for (int t = 0; t < 8; ++t) {
    int f = t * 16 + n16;
    bf16x8 b[4];
#pragma unroll
    for (int ks = 0; ks < 4; ++ks)
      b[ks] = *(const bf16x8*)&s_w[(f << 7) + (((ks * 4 + q) ^ (f & 15)) << 3)];
#pragma unroll
    for (int g = 0; g < 2; ++g) {
      f32x4 acc = {0.f, 0.f, 0.f, 0.f};
#pragma unroll
      for (int ks = 0; ks < 4; ++ks)
        acc = __builtin_amdgcn_mfma_f32_16x16x32_bf16(a[g][ks], b[ks], acc, 0, 0, 0);
#pragma unroll
      for (int r = 0; r < 4; ++r) {
        int n = base + w * 32 + g * 16 + q * 4 + r;
        if (n < nrows) {
          float v = acc[r] + bv[t];
          if (act) v = sspf(v);
          out[(long)n * 128 + f] = v;
        }
      }
    }
  }
}

// ---------------- edge MLP: 16-edge wave-tiles, zero steady-state barriers ----------------
// mode 1: W row (bf16) scatter-stored to Wsrt[inv[e]]    (aggregation in k_e2)
// mode 0: fallback: msg = h[src]*W*cv, atomicAdd into agg (round-3 semantics)
__global__ __launch_bounds__(256, 3) void k_edge2(
    const float* __restrict__ attr, const int* __restrict__ ei,
    const float* __restrict__ ew, const float* __restrict__ w1,
    const float* __restrict__ b1, const float* __restrict__ w2,
    const float* __restrict__ b2, const float* __restrict__ h,
    const int* __restrict__ inv, float* __restrict__ agg,
    unsigned short* __restrict__ Wsrt, int mode)
{
  __shared__ __attribute__((aligned(16))) unsigned short s_w2[128 * 128];   // 32 KB, swizzled
  __shared__ __attribute__((aligned(16))) unsigned short s_scr[4 * 16 * 136]; // 4 waves x 16 rows x 272 B

  const int tid  = threadIdx.x;
  const int w    = tid >> 6;
  const int lane = tid & 63;
  const int q    = lane >> 4;
  const int n16  = lane & 15;

  // stage w2 once (bf16, XOR-chunk swizzle)
  for (int i = tid; i < 128 * 128; i += 256) {
    int f = i >> 7, k = i & 127;
    int pos = (f << 7) + ((((k >> 3) ^ (f & 15)) << 3)) + (k & 7);
    s_w2[pos] = f2b(w2[i]);
  }
  // w1 B-fragments in registers
  bf16x8 w1A[8], w1B[8];
#pragma unroll
  for (int t = 0; t < 8; ++t) {
    int f = t * 16 + n16;
    const float* row = w1 + f * NG;
    union { ushortx8 u; bf16x8 b; } ua, ub;
#pragma unroll
    for (int j = 0; j < 8; ++j) ua.u[j] = f2b(row[q * 8 + j]);
#pragma unroll
    for (int j = 0; j < 8; ++j) { int k = 32 + q * 8 + j; ub.u[j] = (k < NG) ? f2b(row[k]) : (unsigned short)0; }
    w1A[t] = ua.b; w1B[t] = ub.b;
  }
  float b1v[8], b2v[8];
#pragma unroll
  for (int t = 0; t < 8; ++t) {
    b1v[t] = b1[t * 16 + n16];
    b2v[t] = b2[t * 16 + n16];
  }
  __syncthreads();  // s_w2 ready — only barrier in the kernel

  unsigned short* scr = s_scr + w * (16 * 136);
  const int nwaves = EDGE_BLOCKS * 4;
  const int gw = blockIdx.x * 4 + w;

  for (int tile = gw; tile < NTW; tile += nwaves) {
    const int e0 = tile * 16;
    const int er = e0 + n16;
    const float* rp = attr + (long)er * NG;

    // A-fragments directly from global (row = er, k = q*8+j / 32+q*8+j)
    float2 p0 = *(const float2*)(rp + q * 8);
    float2 p1 = *(const float2*)(rp + q * 8 + 2);
    float2 p2 = *(const float2*)(rp + q * 8 + 4);
    float2 p3 = *(const float2*)(rp + q * 8 + 6);
    float2 p4 = {0.f, 0.f}, p5 = {0.f, 0.f}, p6 = {0.f, 0.f}, p7 = {0.f, 0.f};
    if (q < 2) {
      const float* rp2 = rp + 32 + q * 8;
      p4 = *(const float2*)(rp2);
      p5 = *(const float2*)(rp2 + 2);
      p6 = *(const float2*)(rp2 + 4);
      p7 = *(const float2*)(rp2 + 6);
    } else if (q == 2) {
      p4 = *(const float2*)(rp + 48);   // k=48,49 (exactly row end; no OOB)
    }
    union { ushortx8 u; bf16x8 b; } ua, ub;
    ua.u[0] = f2b(p0.x); ua.u[1] = f2b(p0.y); ua.u[2] = f2b(p1.x); ua.u[3] = f2b(p1.y);
    ua.u[4] = f2b(p2.x); ua.u[5] = f2b(p2.y); ua.u[6] = f2b(p3.x); ua.u[7] = f2b(p3.y);
    ub.u[0] = f2b(p4.x); ub.u[1] = f2b(p4.y); ub.u[2] = f2b(p5.x); ub.u[3] = f2b(p5.y);
    ub.u[4] = f2b(p6.x); ub.u[5] = f2b(p6.y); ub.u[6] = f2b(p7.x); ub.u[7] = f2b(p7.y);

    // layer 1 -> h_e into wave-private scratch (row-major, 136-short padded rows)
#pragma unroll
    for (int t = 0; t < 8; ++t) {
      f32x4 acc = {0.f, 0.f, 0.f, 0.f};
      acc = __builtin_amdgcn_mfma_f32_16x16x32_bf16(ua.b, w1A[t], acc, 0, 0, 0);
      acc = __builtin_amdgcn_mfma_f32_16x16x32_bf16(ub.b, w1B[t], acc, 0, 0, 0);
      int f = t * 16 + n16;
#pragma unroll
      for (int r = 0; r < 4; ++r) {
        int row = q * 4 + r;                 // C-layout row = local edge
        scr[row * 136 + f] = f2b(sspf(acc[r] + b1v[t]));
      }
    }
    __builtin_amdgcn_wave_barrier();

    // layer-2 A fragments (cross-lane, wave-synchronous; lgkmcnt orders it)
    bf16x8 a2f[4];
#pragma unroll
    for (int ks = 0; ks < 4; ++ks)
      a2f[ks] = *(const bf16x8*)&scr[n16 * 136 + ks * 32 + q * 8];
    __builtin_amdgcn_wave_barrier();

    int srcv[4], dstv[4]; float cvv[4];
    if (mode == 0) {
#pragma unroll
      for (int r = 0; r < 4; ++r) {
        int e = e0 + q * 4 + r;
        srcv[r] = ei[e];
        dstv[r] = ei[E_NUM + e];
        cvv[r] = 0.5f * (__builtin_amdgcn_cosf(ew[e] * 0.05f) + 1.f);
      }
    }

    // layer 2
#pragma unroll
    for (int t = 0; t < 8; ++t) {
      int f = t * 16 + n16;
      f32x4 acc = {0.f, 0.f, 0.f, 0.f};
#pragma unroll
      for (int ks = 0; ks < 4; ++ks) {
        bf16x8 bb = *(const bf16x8*)&s_w2[(f << 7) + (((ks * 4 + q) ^ (f & 15)) << 3)];
        acc = __builtin_amdgcn_mfma_f32_16x16x32_bf16(a2f[ks], bb, acc, 0, 0, 0);
      }
      if (mode == 1) {
#pragma unroll
        for (int r = 0; r < 4; ++r) {
          int row = q * 4 + r;
          scr[row * 136 + f] = f2b(acc[r] + b2v[t]);   // W row, reuses scratch
        }
      } else {
#pragma unroll
        for (int r = 0; r < 4; ++r) {
          float msg = h[(long)srcv[r] * 128 + f] * (acc[r] + b2v[t]) * cvv[r];
          atomicAdd(&agg[(long)dstv[r] * 128 + f], msg);
        }
      }
    }

    if (mode == 1) {
      __builtin_amdgcn_wave_barrier();
      // scatter-store 16 rows (256 B each) to sorted positions; 4 rows/instr
#pragma unroll
      for (int i = 0; i < 4; ++i) {
        int row = i * 4 + q;
        int pos = inv[e0 + row];
        ushortx8 v = *(const ushortx8*)&scr[row * 136 + n16 * 8];
        *(ushortx8*)(Wsrt + (long)pos * 128 + n16 * 8) = v;
      }
      __builtin_amdgcn_wave_barrier();
    }
  }
}

// ---------------- CSR aggregation: one wave per node, no atomics ----------------
__global__ __launch_bounds__(256) void k_e2(
    const unsigned short* __restrict__ Wsrt, const int* __restrict__ srcS,
    const float* __restrict__ cvS, const int* __restrict__ off,
    const float* __restrict__ h, float* __restrict__ agg)
{
  const int wv = threadIdx.x >> 6, lane = threadIdx.x & 63;
  const int n = blockIdx.x * 4 + wv;
  const int j0 = off[n], j1 = off[n + 1];
  float ax = 0.f, ay = 0.f;
  for (int j = j0; j < j1; ++j) {
    int s = srcS[j];
    float c = cvS[j];
    unsigned wp = *(const unsigned*)(Wsrt + (long)j * 128 + lane * 2);
    float2 hp = *(const float2*)(h + (long)s * 128 + lane * 2);
    ax += c * hp.x * b2f((unsigned short)(wp & 0xffffu));
    ay += c * hp.y * b2f((unsigned short)(wp >> 16));
  }
  float2 o; o.x = ax; o.y = ay;
  *(float2*)(agg + (long)n * 128 + lane * 2) = o;
}

extern "C" void kernel_launch(void* const* d_in, const int* in_sizes, int n_in,
                              void* d_out, int out_size, void* d_ws, size_t ws_size,
                              hipStream_t stream) {
  const float* x     = (const float*)d_in[0];
  const int*   ei    = (const int*)  d_in[1];
  const float* ew    = (const float*)d_in[2];
  const float* attr  = (const float*)d_in[3];
  const float* w1    = (const float*)d_in[4];
  const float* b1    = (const float*)d_in[5];
  const float* w2    = (const float*)d_in[6];
  const float* b2    = (const float*)d_in[7];
  const float* lin1w = (const float*)d_in[8];
  const float* lin2w = (const float*)d_in[9];
  const float* lin2b = (const float*)d_in[10];
  const float* linw  = (const float*)d_in[11];
  const float* linb  = (const float*)d_in[12];
  float* out = (float*)d_out;

  // workspace layout
  char* base = (char*)d_ws;
  float* agg    = (float*)base;                               // NN*128 f32
  float* h      = agg + (size_t)NN * 128;                     // NN*128 f32 (reused as h2)
  int*   counts = (int*)(h + (size_t)NN * 128);               // NN
  int*   cursor = counts + NN;                                // NN
  int*   off    = cursor + NN;                                // NN+1
  int*   inv    = off + NN + 1;                               // E
  int*   srcS   = inv + E_NUM;                                // E
  float* cvS    = (float*)(srcS + E_NUM);                     // E
  size_t head   = (size_t)((char*)(cvS + E_NUM) - base);
  size_t woff   = (head + 255) & ~(size_t)255;                // 256-B align
  unsigned short* Wsrt = (unsigned short*)(base + woff);      // E*128 bf16
  size_t need = woff + (size_t)E_NUM * 128 * sizeof(unsigned short);
  const int mode = (ws_size >= need) ? 1 : 0;

  const int gemm_grid = (NN + 127) / 128;
  if (mode == 1) {
    (void)hipMemsetAsync(counts, 0, (size_t)NN * sizeof(int), stream);
    k_hist<<<(E_NUM + 255) / 256, 256, 0, stream>>>(ei, counts);
    k_scan<<<1, 1024, 0, stream>>>(counts, cursor, off);
    k_scatter2<<<(E_NUM + 255) / 256, 256, 0, stream>>>(ei, ew, cursor, inv, srcS, cvS);
    k_edge2<<<EDGE_BLOCKS, 256, 0, stream>>>(attr, ei, ew, w1, b1, w2, b2, h, inv, agg, Wsrt, 1);
    k_mfma_gemm<<<gemm_grid, 256, 0, stream>>>(x, lin1w, nullptr, h, 0, NN);
    k_e2<<<NN / 4, 256, 0, stream>>>(Wsrt, srcS, cvS, off, h, agg);
  } else {
    (void)hipMemsetAsync(agg, 0, (size_t)NN * 128 * sizeof(float), stream);
    k_mfma_gemm<<<gemm_grid, 256, 0, stream>>>(x, lin1w, nullptr, h, 0, NN);
    k_edge2<<<EDGE_BLOCKS, 256, 0, stream>>>(attr, ei, ew, w1, b1, w2, b2, h, inv, agg, Wsrt, 0);
  }
  k_mfma_gemm<<<gemm_grid, 256, 0, stream>>>(agg, lin2w, lin2b, h, 1, NN);
  k_mfma_gemm<<<gemm_grid, 256, 0, stream>>>(h, linw, linb, out, 0, NN);
}

// Round 6
// 668.790 us; speedup vs baseline: 1.7092x; 1.0670x over previous
//
#include <hip/hip_runtime.h>
#include <hip/hip_bf16.h>
#include <math.h>

#define E_NUM 800000
#define NN 50000
#define NG 50
#define NTW (E_NUM / 16)        // 16-edge wave-tiles
#define EDGE_BLOCKS 768         // 3 blocks/CU

typedef __bf16 bf16x8 __attribute__((ext_vector_type(8)));
typedef float f32x4 __attribute__((ext_vector_type(4)));
typedef unsigned short ushortx8 __attribute__((ext_vector_type(8)));

__device__ __forceinline__ unsigned short f2b(float f) {
  union { float f; unsigned u; } v; v.f = f;
  unsigned u = v.u;
  u += 0x7fffu + ((u >> 16) & 1u);
  return (unsigned short)(u >> 16);
}
__device__ __forceinline__ float b2f(unsigned short u) {
  union { unsigned u; float f; } v; v.u = ((unsigned)u) << 16; return v.f;
}
// shifted softplus via hw exp2/log2
__device__ __forceinline__ float sspf(float v) {
  float e = __builtin_amdgcn_exp2f(-1.4426950408889634f * fabsf(v));
  return fmaxf(v, 0.f) + 0.6931471805599453f * __builtin_amdgcn_logf(fmaf(0.5f, e, 0.5f));
}

// ---------------- counting sort by dst ----------------
__global__ __launch_bounds__(256) void k_hist(const int* __restrict__ ei, int* __restrict__ counts) {
  int e = blockIdx.x * 256 + threadIdx.x;
  if (e < E_NUM) atomicAdd(&counts[ei[E_NUM + e]], 1);
}

__global__ __launch_bounds__(1024) void k_scan(const int* __restrict__ counts,
                                               int* __restrict__ cursor, int* __restrict__ off) {
  __shared__ int tot[1024];
  const int t = threadIdx.x;
  const int C = (NN + 1023) >> 10;  // 49
  int lo = t * C, hi = lo + C; if (hi > NN) hi = NN; if (lo > NN) lo = NN;
  int s = 0;
  for (int i = lo; i < hi; ++i) s += counts[i];
  tot[t] = s;
  __syncthreads();
  int mine = s;
  for (int o = 1; o < 1024; o <<= 1) {
    int v = (t >= o) ? tot[t - o] : 0;
    __syncthreads();
    tot[t] += v;
    __syncthreads();
  }
  int run = tot[t] - mine;
  for (int i = lo; i < hi; ++i) { int c = counts[i]; cursor[i] = run; off[i] = run; run += c; }
  if (t == 1023) off[NN] = E_NUM;
}

__global__ __launch_bounds__(256) void k_scatter2(const int* __restrict__ ei,
                                                  int* __restrict__ cursor, int* __restrict__ inv,
                                                  int* __restrict__ srcS) {
  int e = blockIdx.x * 256 + threadIdx.x;
  if (e < E_NUM) {
    int d = ei[E_NUM + e];
    int pos = atomicAdd(&cursor[d], 1);
    inv[e] = pos;
    srcS[pos] = ei[e];
  }
}

// ---------------- node GEMM (bf16 MFMA, 128-node blocks) ----------------
__global__ __launch_bounds__(256) void k_mfma_gemm(
    const float* __restrict__ X, const float* __restrict__ Wm,
    const float* __restrict__ bias, float* __restrict__ out, int act, int nrows)
{
  __shared__ __attribute__((aligned(16))) unsigned short s_x[128 * 128];
  __shared__ __attribute__((aligned(16))) unsigned short s_w[128 * 128];
  const int tid = threadIdx.x;
  const int w = tid >> 6, lane = tid & 63, q = lane >> 4, n16 = lane & 15;
  const int base = blockIdx.x * 128;

  for (int c = tid; c < 128 * 16; c += 256) {
    int f = c >> 4, ch = c & 15;
    const float4* wp = (const float4*)(Wm + f * 128 + ch * 8);
    float4 v0 = wp[0], v1 = wp[1];
    ushortx8 v = { f2b(v0.x), f2b(v0.y), f2b(v0.z), f2b(v0.w),
                   f2b(v1.x), f2b(v1.y), f2b(v1.z), f2b(v1.w) };
    *(ushortx8*)&s_w[(f << 7) + ((ch ^ (f & 15)) << 3)] = v;
  }
  for (int c = tid; c < 128 * 16; c += 256) {
    int r = c >> 4, ch = c & 15;
    int n = base + r;
    float4 v0 = {0.f, 0.f, 0.f, 0.f}, v1 = v0;
    if (n < nrows) {
      const float4* xp = (const float4*)(X + (long)n * 128 + ch * 8);
      v0 = xp[0]; v1 = xp[1];
    }
    ushortx8 v = { f2b(v0.x), f2b(v0.y), f2b(v0.z), f2b(v0.w),
                   f2b(v1.x), f2b(v1.y), f2b(v1.z), f2b(v1.w) };
    *(ushortx8*)&s_x[(r << 7) + ((ch ^ (r & 15)) << 3)] = v;
  }
  __syncthreads();

  float bv[8];
#pragma unroll
  for (int t = 0; t < 8; ++t) bv[t] = bias ? bias[t * 16 + n16] : 0.f;

  bf16x8 a[2][4];
#pragma unroll
  for (int g = 0; g < 2; ++g) {
    int r = w * 32 + g * 16 + n16;
#pragma unroll
    for (int ks = 0; ks < 4; ++ks)
      a[g][ks] = *(const bf16x8*)&s_x[(r << 7) + (((ks * 4 + q) ^ (r & 15)) << 3)];
  }
#pragma unroll
  for (int t = 0; t < 8; ++t) {
    int f = t * 16 + n16;
    bf16x8 b[4];
#pragma unroll
    for (int ks = 0; ks < 4; ++ks)
      b[ks] = *(const bf16x8*)&s_w[(f << 7) + (((ks * 4 + q) ^ (f & 15)) << 3)];
#pragma unroll
    for (int g = 0; g < 2; ++g) {
      f32x4 acc = {0.f, 0.f, 0.f, 0.f};
#pragma unroll
      for (int ks = 0; ks < 4; ++ks)
        acc = __builtin_amdgcn_mfma_f32_16x16x32_bf16(a[g][ks], b[ks], acc, 0, 0, 0);
#pragma unroll
      for (int r = 0; r < 4; ++r) {
        int n = base + w * 32 + g * 16 + q * 4 + r;
        if (n < nrows) {
          float v = acc[r] + bv[t];
          if (act) v = sspf(v);
          out[(long)n * 128 + f] = v;
        }
      }
    }
  }
}

// ---------------- edge MLP: 16-edge wave-tiles, zero steady-state barriers ----------------
// mode 1: (W*C) row (bf16) scatter-stored to Wsrt[inv[e]]  (aggregation in k_e2)
// mode 0: fallback: msg = h[src]*W*cv, atomicAdd into agg
__global__ __launch_bounds__(256, 3) void k_edge2(
    const float* __restrict__ attr, const int* __restrict__ ei,
    const float* __restrict__ ew, const float* __restrict__ w1,
    const float* __restrict__ b1, const float* __restrict__ w2,
    const float* __restrict__ b2, const float* __restrict__ h,
    const int* __restrict__ inv, float* __restrict__ agg,
    unsigned short* __restrict__ Wsrt, int mode)
{
  __shared__ __attribute__((aligned(16))) unsigned short s_w2[128 * 128];     // 32 KB, swizzled
  __shared__ __attribute__((aligned(16))) unsigned short s_scr[4 * 16 * 136]; // 4 waves x 16 rows x 272 B

  const int tid  = threadIdx.x;
  const int w    = tid >> 6;
  const int lane = tid & 63;
  const int q    = lane >> 4;
  const int n16  = lane & 15;

  // stage w2 once (bf16, XOR-chunk swizzle)
  for (int i = tid; i < 128 * 128; i += 256) {
    int f = i >> 7, k = i & 127;
    int pos = (f << 7) + ((((k >> 3) ^ (f & 15)) << 3)) + (k & 7);
    s_w2[pos] = f2b(w2[i]);
  }
  // w1 B-fragments in registers
  bf16x8 w1A[8], w1B[8];
#pragma unroll
  for (int t = 0; t < 8; ++t) {
    int f = t * 16 + n16;
    const float* row = w1 + f * NG;
    union { ushortx8 u; bf16x8 b; } ua, ub;
#pragma unroll
    for (int j = 0; j < 8; ++j) ua.u[j] = f2b(row[q * 8 + j]);
#pragma unroll
    for (int j = 0; j < 8; ++j) { int k = 32 + q * 8 + j; ub.u[j] = (k < NG) ? f2b(row[k]) : (unsigned short)0; }
    w1A[t] = ua.b; w1B[t] = ub.b;
  }
  float b1v[8], b2v[8];
#pragma unroll
  for (int t = 0; t < 8; ++t) {
    b1v[t] = b1[t * 16 + n16];
    b2v[t] = b2[t * 16 + n16];
  }
  __syncthreads();  // s_w2 ready — only barrier in the kernel

  unsigned short* scr = s_scr + w * (16 * 136);
  const int nwaves = EDGE_BLOCKS * 4;
  const int gw = blockIdx.x * 4 + w;

  for (int tile = gw; tile < NTW; tile += nwaves) {
    const int e0 = tile * 16;
    const int er = e0 + n16;
    const float* rp = attr + (long)er * NG;

    // A-fragments directly from global
    float2 p0 = *(const float2*)(rp + q * 8);
    float2 p1 = *(const float2*)(rp + q * 8 + 2);
    float2 p2 = *(const float2*)(rp + q * 8 + 4);
    float2 p3 = *(const float2*)(rp + q * 8 + 6);
    float2 p4 = {0.f, 0.f}, p5 = {0.f, 0.f}, p6 = {0.f, 0.f}, p7 = {0.f, 0.f};
    if (q < 2) {
      const float* rp2 = rp + 32 + q * 8;
      p4 = *(const float2*)(rp2);
      p5 = *(const float2*)(rp2 + 2);
      p6 = *(const float2*)(rp2 + 4);
      p7 = *(const float2*)(rp2 + 6);
    } else if (q == 2) {
      p4 = *(const float2*)(rp + 48);   // k=48,49
    }
    union { ushortx8 u; bf16x8 b; } ua, ub;
    ua.u[0] = f2b(p0.x); ua.u[1] = f2b(p0.y); ua.u[2] = f2b(p1.x); ua.u[3] = f2b(p1.y);
    ua.u[4] = f2b(p2.x); ua.u[5] = f2b(p2.y); ua.u[6] = f2b(p3.x); ua.u[7] = f2b(p3.y);
    ub.u[0] = f2b(p4.x); ub.u[1] = f2b(p4.y); ub.u[2] = f2b(p5.x); ub.u[3] = f2b(p5.y);
    ub.u[4] = f2b(p6.x); ub.u[5] = f2b(p6.y); ub.u[6] = f2b(p7.x); ub.u[7] = f2b(p7.y);

    // layer 1 -> h_e into wave-private scratch
#pragma unroll
    for (int t = 0; t < 8; ++t) {
      f32x4 acc = {0.f, 0.f, 0.f, 0.f};
      acc = __builtin_amdgcn_mfma_f32_16x16x32_bf16(ua.b, w1A[t], acc, 0, 0, 0);
      acc = __builtin_amdgcn_mfma_f32_16x16x32_bf16(ub.b, w1B[t], acc, 0, 0, 0);
      int f = t * 16 + n16;
#pragma unroll
      for (int r = 0; r < 4; ++r) {
        int row = q * 4 + r;
        scr[row * 136 + f] = f2b(sspf(acc[r] + b1v[t]));
      }
    }
    __builtin_amdgcn_wave_barrier();

    // layer-2 A fragments
    bf16x8 a2f[4];
#pragma unroll
    for (int ks = 0; ks < 4; ++ks)
      a2f[ks] = *(const bf16x8*)&scr[n16 * 136 + ks * 32 + q * 8];
    __builtin_amdgcn_wave_barrier();

    // cutoff per edge row (needed in both modes; folded into W in mode 1)
    float cvv[4];
#pragma unroll
    for (int r = 0; r < 4; ++r)
      cvv[r] = 0.5f * (__builtin_amdgcn_cosf(ew[e0 + q * 4 + r] * 0.05f) + 1.f);

    int srcv[4], dstv[4];
    if (mode == 0) {
#pragma unroll
      for (int r = 0; r < 4; ++r) {
        srcv[r] = ei[e0 + q * 4 + r];
        dstv[r] = ei[E_NUM + e0 + q * 4 + r];
      }
    }

    // layer 2
#pragma unroll
    for (int t = 0; t < 8; ++t) {
      int f = t * 16 + n16;
      f32x4 acc = {0.f, 0.f, 0.f, 0.f};
#pragma unroll
      for (int ks = 0; ks < 4; ++ks) {
        bf16x8 bb = *(const bf16x8*)&s_w2[(f << 7) + (((ks * 4 + q) ^ (f & 15)) << 3)];
        acc = __builtin_amdgcn_mfma_f32_16x16x32_bf16(a2f[ks], bb, acc, 0, 0, 0);
      }
      if (mode == 1) {
#pragma unroll
        for (int r = 0; r < 4; ++r) {
          int row = q * 4 + r;
          scr[row * 136 + f] = f2b((acc[r] + b2v[t]) * cvv[r]);  // W*C, reuses scratch
        }
      } else {
#pragma unroll
        for (int r = 0; r < 4; ++r) {
          float msg = h[(long)srcv[r] * 128 + f] * (acc[r] + b2v[t]) * cvv[r];
          atomicAdd(&agg[(long)dstv[r] * 128 + f], msg);
        }
      }
    }

    if (mode == 1) {
      __builtin_amdgcn_wave_barrier();
      // scatter-store 16 rows (256 B each) to sorted positions; nontemporal
#pragma unroll
      for (int i = 0; i < 4; ++i) {
        int row = i * 4 + q;
        int pos = inv[e0 + row];
        ushortx8 v = *(const ushortx8*)&scr[row * 136 + n16 * 8];
        __builtin_nontemporal_store(v, (ushortx8*)(Wsrt + (long)pos * 128 + n16 * 8));
      }
      __builtin_amdgcn_wave_barrier();
    }
  }
}

// ---------------- CSR aggregation: one wave per node, 4x-batched loads, no atomics ----------------
__global__ __launch_bounds__(256) void k_e2(
    const unsigned short* __restrict__ Wsrt, const int* __restrict__ srcS,
    const int* __restrict__ off, const float* __restrict__ h, float* __restrict__ agg)
{
  const int wv = threadIdx.x >> 6, lane = threadIdx.x & 63;
  const int n = blockIdx.x * 4 + wv;
  const int j0 = off[n], j1 = off[n + 1];
  float ax = 0.f, ay = 0.f;
  int j = j0;
  for (; j + 4 <= j1; j += 4) {
    int s0 = srcS[j], s1 = srcS[j + 1], s2 = srcS[j + 2], s3 = srcS[j + 3];
    unsigned w0 = __builtin_nontemporal_load((const unsigned*)(Wsrt + (long)(j    ) * 128) + lane);
    unsigned w1_ = __builtin_nontemporal_load((const unsigned*)(Wsrt + (long)(j + 1) * 128) + lane);
    unsigned w2_ = __builtin_nontemporal_load((const unsigned*)(Wsrt + (long)(j + 2) * 128) + lane);
    unsigned w3_ = __builtin_nontemporal_load((const unsigned*)(Wsrt + (long)(j + 3) * 128) + lane);
    float2 h0 = *(const float2*)(h + (long)s0 * 128 + lane * 2);
    float2 h1 = *(const float2*)(h + (long)s1 * 128 + lane * 2);
    float2 h2 = *(const float2*)(h + (long)s2 * 128 + lane * 2);
    float2 h3 = *(const float2*)(h + (long)s3 * 128 + lane * 2);
    ax += h0.x * b2f((unsigned short)(w0 & 0xffffu)) + h1.x * b2f((unsigned short)(w1_ & 0xffffu))
        + h2.x * b2f((unsigned short)(w2_ & 0xffffu)) + h3.x * b2f((unsigned short)(w3_ & 0xffffu));
    ay += h0.y * b2f((unsigned short)(w0 >> 16)) + h1.y * b2f((unsigned short)(w1_ >> 16))
        + h2.y * b2f((unsigned short)(w2_ >> 16)) + h3.y * b2f((unsigned short)(w3_ >> 16));
  }
  for (; j < j1; ++j) {
    int s = srcS[j];
    unsigned wp = __builtin_nontemporal_load((const unsigned*)(Wsrt + (long)j * 128) + lane);
    float2 hp = *(const float2*)(h + (long)s * 128 + lane * 2);
    ax += hp.x * b2f((unsigned short)(wp & 0xffffu));
    ay += hp.y * b2f((unsigned short)(wp >> 16));
  }
  float2 o; o.x = ax; o.y = ay;
  *(float2*)(agg + (long)n * 128 + lane * 2) = o;
}

extern "C" void kernel_launch(void* const* d_in, const int* in_sizes, int n_in,
                              void* d_out, int out_size, void* d_ws, size_t ws_size,
                              hipStream_t stream) {
  const float* x     = (const float*)d_in[0];
  const int*   ei    = (const int*)  d_in[1];
  const float* ew    = (const float*)d_in[2];
  const float* attr  = (const float*)d_in[3];
  const float* w1    = (const float*)d_in[4];
  const float* b1    = (const float*)d_in[5];
  const float* w2    = (const float*)d_in[6];
  const float* b2    = (const float*)d_in[7];
  const float* lin1w = (const float*)d_in[8];
  const float* lin2w = (const float*)d_in[9];
  const float* lin2b = (const float*)d_in[10];
  const float* linw  = (const float*)d_in[11];
  const float* linb  = (const float*)d_in[12];
  float* out = (float*)d_out;

  // workspace layout
  char* base = (char*)d_ws;
  float* agg    = (float*)base;                               // NN*128 f32
  float* h      = agg + (size_t)NN * 128;                     // NN*128 f32 (reused as h2)
  int*   counts = (int*)(h + (size_t)NN * 128);               // NN
  int*   cursor = counts + NN;                                // NN
  int*   off    = cursor + NN;                                // NN+1
  int*   inv    = off + NN + 1;                               // E
  int*   srcS   = inv + E_NUM;                                // E
  size_t head   = (size_t)((char*)(srcS + E_NUM) - base);
  size_t woff   = (head + 255) & ~(size_t)255;                // 256-B align
  unsigned short* Wsrt = (unsigned short*)(base + woff);      // E*128 bf16
  size_t need = woff + (size_t)E_NUM * 128 * sizeof(unsigned short);
  const int mode = (ws_size >= need) ? 1 : 0;

  const int gemm_grid = (NN + 127) / 128;
  if (mode == 1) {
    (void)hipMemsetAsync(counts, 0, (size_t)NN * sizeof(int), stream);
    k_hist<<<(E_NUM + 255) / 256, 256, 0, stream>>>(ei, counts);
    k_scan<<<1, 1024, 0, stream>>>(counts, cursor, off);
    k_scatter2<<<(E_NUM + 255) / 256, 256, 0, stream>>>(ei, cursor, inv, srcS);
    k_edge2<<<EDGE_BLOCKS, 256, 0, stream>>>(attr, ei, ew, w1, b1, w2, b2, h, inv, agg, Wsrt, 1);
    k_mfma_gemm<<<gemm_grid, 256, 0, stream>>>(x, lin1w, nullptr, h, 0, NN);
    k_e2<<<NN / 4, 256, 0, stream>>>(Wsrt, srcS, off, h, agg);
  } else {
    (void)hipMemsetAsync(agg, 0, (size_t)NN * 128 * sizeof(float), stream);
    k_mfma_gemm<<<gemm_grid, 256, 0, stream>>>(x, lin1w, nullptr, h, 0, NN);
    k_edge2<<<EDGE_BLOCKS, 256, 0, stream>>>(attr, ei, ew, w1, b1, w2, b2, h, inv, agg, Wsrt, 0);
  }
  k_mfma_gemm<<<gemm_grid, 256, 0, stream>>>(agg, lin2w, lin2b, h, 1, NN);
  k_mfma_gemm<<<gemm_grid, 256, 0, stream>>>(h, linw, linb, out, 0, NN);
}